// Round 7
// baseline (399.085 us; speedup 1.0000x reference)
//
#include <hip/hip_runtime.h>
#include <cstddef>

// Problem shape (fixed): N=50000, K=16, C_IN=128, C2=256, C_OUT=128.
#define C_IN  128
#define C2    256
#define C_OUT 128
#define KNBR  16

typedef unsigned short u16;
typedef __attribute__((ext_vector_type(8))) short bf16x8;   // 8 bf16 (4 VGPRs)
typedef __attribute__((ext_vector_type(4))) float f32x4;

__device__ __forceinline__ float bf2f(u16 h) {
    return __uint_as_float(((unsigned int)h) << 16);
}
__device__ __forceinline__ u16 f2bf(float x) {
    unsigned int u = __float_as_uint(x);
    return (u16)((u + 0x7fffu + ((u >> 16) & 1u)) >> 16);
}

// Transpose + convert weights to bf16, n-major [N][K].
__global__ void prep_k(const float* __restrict__ W1, const float* __restrict__ Ws,
                       const float* __restrict__ Wm, u16* __restrict__ W1t,
                       u16* __restrict__ Wst, u16* __restrict__ Wmt)
{
    const int n = blockIdx.x, t = threadIdx.x;
    if (blockIdx.y == 0) {
        if (t < 128) W1t[n * 128 + t] = f2bf(W1[t * 256 + n]);
    } else if (blockIdx.y == 1) {
        Wst[n * 256 + t] = f2bf(Ws[t * 256 + n]);
    } else {
        if (n < 128) Wmt[n * 256 + t] = f2bf(Wm[t * 128 + n]);
    }
}

// Fused MLP, 64-row blocks (2 blocks/CU):
//   x  = BN(relu(F @ W1 + b1));  ey = exp(x @ Ws)
// packed row (512 u16): [ey[0..255] | x[0..255]], both bf16.
// All global output via coalesced LDS->global flushes (no scattered stores).
__global__ __launch_bounds__(256)
void mlp_k(const float* __restrict__ F, const u16* __restrict__ W1t,
           const u16* __restrict__ Wst, const float* __restrict__ bias,
           const float* __restrict__ gamma, const float* __restrict__ beta,
           const float* __restrict__ mean, const float* __restrict__ var,
           u16* __restrict__ packed, int N)
{
    __shared__ u16 As[64][136];    // features tile, full K=128
    __shared__ u16 Bs[128][72];    // weight k-slice staging
    __shared__ u16 xs[64][272];    // x tile (then reused for ey)

    const int tid = threadIdx.x;
    const int w = tid >> 6, l = tid & 63, q = l >> 4, r = l & 15;
    const int wm = w & 1, wn = w >> 1;
    const int m0 = blockIdx.x * 64;

    // stage As: 64 x 128 fp32 -> bf16
    #pragma unroll
    for (int i = 0; i < 8; i++) {
        int idx = tid + i * 256;
        int row = idx >> 5, c4 = (idx & 31) * 4;
        int gm = m0 + row;
        float4 v = make_float4(0.f, 0.f, 0.f, 0.f);
        if (gm < N) v = *(const float4*)(F + (size_t)gm * C_IN + c4);
        ushort4 h;
        h.x = f2bf(v.x); h.y = f2bf(v.y); h.z = f2bf(v.z); h.w = f2bf(v.w);
        *(ushort4*)&As[row][c4] = h;
    }

    // ---- GEMM1: both 128-col halves accumulated in registers ----
    f32x4 acc1[2][2][4] = {};
    #pragma unroll 1
    for (int nh = 0; nh < 2; nh++) {
        #pragma unroll 1
        for (int k0 = 0; k0 < C_IN; k0 += 64) {
            __syncthreads();
            #pragma unroll
            for (int i = 0; i < 4; i++) {
                int idx = tid + i * 256;
                int row = idx >> 3, g = (idx & 7) * 8;
                *(uint4*)&Bs[row][g] = *(const uint4*)(
                    W1t + (size_t)(nh * 128 + row) * C_IN + k0 + g);
            }
            __syncthreads();
            #pragma unroll
            for (int h = 0; h < 2; h++) {
                bf16x8 af[2], bfr[4];
                #pragma unroll
                for (int i = 0; i < 2; i++)
                    af[i] = *(const bf16x8*)&As[wm * 32 + i * 16 + r][k0 + h * 32 + q * 8];
                #pragma unroll
                for (int j = 0; j < 4; j++)
                    bfr[j] = *(const bf16x8*)&Bs[wn * 64 + j * 16 + r][h * 32 + q * 8];
                #pragma unroll
                for (int i = 0; i < 2; i++)
                    #pragma unroll
                    for (int j = 0; j < 4; j++)
                        acc1[nh][i][j] = __builtin_amdgcn_mfma_f32_16x16x32_bf16(
                            af[i], bfr[j], acc1[nh][i][j], 0, 0, 0);
            }
        }
    }
    // epilogue 1: BN(relu(z+b1)) -> xs
    #pragma unroll
    for (int nh = 0; nh < 2; nh++)
        #pragma unroll
        for (int j = 0; j < 4; j++) {
            const int ch = nh * 128 + wn * 64 + j * 16 + r;
            const float bi = bias[ch], be = beta[ch], mu = mean[ch];
            const float iv = gamma[ch] * rsqrtf(var[ch] + 1e-5f);
            #pragma unroll
            for (int i = 0; i < 2; i++)
                #pragma unroll
                for (int p = 0; p < 4; p++) {
                    const int ml = wm * 32 + i * 16 + q * 4 + p;
                    float x = fmaxf(acc1[nh][i][j][p] + bi, 0.f);
                    x = (x - mu) * iv + be;
                    xs[ml][ch] = f2bf(x);
                }
        }
    __syncthreads();
    // flush x-half coalesced (uint4 = 8 bf16)
    #pragma unroll
    for (int i = 0; i < 8; i++) {
        int idx = tid + i * 256;
        int row = idx >> 5, g = (idx & 31) * 8;
        if (m0 + row < N)
            *(uint4*)(packed + (size_t)(m0 + row) * 512 + 256 + g) =
                *(const uint4*)&xs[row][g];
    }

    // ---- GEMM2: ey = exp(x @ Ws), A from xs ----
    f32x4 acc2[2][2][4] = {};
    #pragma unroll 1
    for (int nh = 0; nh < 2; nh++) {
        #pragma unroll 1
        for (int k0 = 0; k0 < C2; k0 += 64) {
            __syncthreads();
            #pragma unroll
            for (int i = 0; i < 4; i++) {
                int idx = tid + i * 256;
                int row = idx >> 3, g = (idx & 7) * 8;
                *(uint4*)&Bs[row][g] = *(const uint4*)(
                    Wst + (size_t)(nh * 128 + row) * C2 + k0 + g);
            }
            __syncthreads();
            #pragma unroll
            for (int h = 0; h < 2; h++) {
                bf16x8 af[2], bfr[4];
                #pragma unroll
                for (int i = 0; i < 2; i++)
                    af[i] = *(const bf16x8*)&xs[wm * 32 + i * 16 + r][k0 + h * 32 + q * 8];
                #pragma unroll
                for (int j = 0; j < 4; j++)
                    bfr[j] = *(const bf16x8*)&Bs[wn * 64 + j * 16 + r][h * 32 + q * 8];
                #pragma unroll
                for (int i = 0; i < 2; i++)
                    #pragma unroll
                    for (int j = 0; j < 4; j++)
                        acc2[nh][i][j] = __builtin_amdgcn_mfma_f32_16x16x32_bf16(
                            af[i], bfr[j], acc2[nh][i][j], 0, 0, 0);
            }
        }
    }
    __syncthreads();   // all xs reads done before overwrite
    // epilogue 2: ey -> xs (reuse)
    #pragma unroll
    for (int nh = 0; nh < 2; nh++)
        #pragma unroll
        for (int j = 0; j < 4; j++) {
            const int ch = nh * 128 + wn * 64 + j * 16 + r;
            #pragma unroll
            for (int i = 0; i < 2; i++)
                #pragma unroll
                for (int p = 0; p < 4; p++) {
                    const int ml = wm * 32 + i * 16 + q * 4 + p;
                    xs[ml][ch] = f2bf(__expf(acc2[nh][i][j][p]));
                }
        }
    __syncthreads();
    // flush ey-half coalesced
    #pragma unroll
    for (int i = 0; i < 8; i++) {
        int idx = tid + i * 256;
        int row = idx >> 5, g = (idx & 31) * 8;
        if (m0 + row < N)
            *(uint4*)(packed + (size_t)(m0 + row) * 512 + g) =
                *(const uint4*)&xs[row][g];
    }
}

// Fused gather + softmax-pool + output GEMM, 64 points/block (4 blocks/CU).
// Phase 1: wave w pools points w*16..w*16+15 -> fs (LDS, bf16).
// Phase 2: out[64 x 128] = fs @ Wm + bm; Wm B-frags direct from L2.
__global__ __launch_bounds__(256, 4)
void gout_k(const u16* __restrict__ packed, const int* __restrict__ nidx,
            const u16* __restrict__ Wmt, const float* __restrict__ bm,
            float* __restrict__ out, int N)
{
    __shared__ int rows[64 * KNBR];   // 4 KB
    __shared__ u16 fs[64][272];       // 34.8 KB (reused as fp32 out tile)
    const int tid = threadIdx.x;
    const int w = tid >> 6, l = tid & 63, q = l >> 4, r = l & 15;
    const int wm = w & 1, wn = w >> 1;
    const int m0 = blockIdx.x * 64;

    {   // stage neighbor indices (4 per thread, guarded int4)
        int gi = m0 * KNBR + tid * 4;
        int4 v;
        if (gi + 3 < N * KNBR) v = *(const int4*)(nidx + gi);
        else {
            v.x = (gi + 0 < N * KNBR) ? nidx[gi + 0] : 0;
            v.y = (gi + 1 < N * KNBR) ? nidx[gi + 1] : 0;
            v.z = (gi + 2 < N * KNBR) ? nidx[gi + 2] : 0;
            v.w = (gi + 3 < N * KNBR) ? nidx[gi + 3] : 0;
        }
        *(int4*)&rows[tid * 4] = v;
    }
    __syncthreads();

    // phase 1: gather + pool
    #pragma unroll 1
    for (int pi = 0; pi < 16; pi++) {
        const int lp = w * 16 + pi;
        ushort4 eh[KNBR], xh[KNBR];
        #pragma unroll
        for (int k = 0; k < KNBR; k++) {
            const size_t base = (size_t)rows[lp * KNBR + k] * 512;
            eh[k] = *(const ushort4*)(packed + base + l * 4);
            xh[k] = *(const ushort4*)(packed + base + 256 + l * 4);
        }
        float d0 = 0.f, d1 = 0.f, d2 = 0.f, d3 = 0.f;
        float u0 = 0.f, u1 = 0.f, u2 = 0.f, u3 = 0.f;
        #pragma unroll
        for (int k = 0; k < KNBR; k++) {
            float e0 = bf2f(eh[k].x), e1 = bf2f(eh[k].y);
            float e2 = bf2f(eh[k].z), e3 = bf2f(eh[k].w);
            d0 += e0; d1 += e1; d2 += e2; d3 += e3;
            u0 = fmaf(e0, bf2f(xh[k].x), u0);
            u1 = fmaf(e1, bf2f(xh[k].y), u1);
            u2 = fmaf(e2, bf2f(xh[k].z), u2);
            u3 = fmaf(e3, bf2f(xh[k].w), u3);
        }
        ushort4 o;
        o.x = f2bf(u0 / d0); o.y = f2bf(u1 / d1);
        o.z = f2bf(u2 / d2); o.w = f2bf(u3 / d3);
        *(ushort4*)&fs[lp][l * 4] = o;
    }
    __syncthreads();

    // phase 2: out tile GEMM (A from fs, B direct from L2, depth-1 pipeline)
    f32x4 acc[2][4] = {};
    uint4 bcur[4], bnxt[4];
    #pragma unroll
    for (int j = 0; j < 4; j++)
        bcur[j] = *(const uint4*)(Wmt + (size_t)(wn * 64 + j * 16 + r) * C2 + q * 8);
    #pragma unroll 1
    for (int ks = 0; ks < 8; ks++) {
        if (ks < 7) {
            #pragma unroll
            for (int j = 0; j < 4; j++)
                bnxt[j] = *(const uint4*)(
                    Wmt + (size_t)(wn * 64 + j * 16 + r) * C2 + (ks + 1) * 32 + q * 8);
        }
        bf16x8 af[2];
        #pragma unroll
        for (int i = 0; i < 2; i++)
            af[i] = *(const bf16x8*)&fs[wm * 32 + i * 16 + r][ks * 32 + q * 8];
        #pragma unroll
        for (int i = 0; i < 2; i++)
            #pragma unroll
            for (int j = 0; j < 4; j++)
                acc[i][j] = __builtin_amdgcn_mfma_f32_16x16x32_bf16(
                    af[i], *(const bf16x8*)&bcur[j], acc[i][j], 0, 0, 0);
        #pragma unroll
        for (int j = 0; j < 4; j++) bcur[j] = bnxt[j];
    }
    __syncthreads();   // fs reads done before overwrite

    // epilogue -> fs reused as fp32 [64][128] tile (32 KB), then coalesced flush
    float* fsf = (float*)&fs[0][0];
    #pragma unroll
    for (int j = 0; j < 4; j++) {
        const int ch = wn * 64 + j * 16 + r;
        const float bo = bm[ch];
        #pragma unroll
        for (int i = 0; i < 2; i++)
            #pragma unroll
            for (int p = 0; p < 4; p++) {
                const int ml = wm * 32 + i * 16 + q * 4 + p;
                fsf[ml * C_OUT + ch] = acc[i][j][p] + bo;
            }
    }
    __syncthreads();
    #pragma unroll
    for (int i = 0; i < 8; i++) {
        int idx = tid + i * 256;
        int row = idx >> 5, c4 = (idx & 31) * 4;
        if (m0 + row < N)
            *(float4*)(out + (size_t)(m0 + row) * C_OUT + c4) =
                *(const float4*)&fsf[row * C_OUT + c4];
    }
}

extern "C" void kernel_launch(void* const* d_in, const int* in_sizes, int n_in,
                              void* d_out, int out_size, void* d_ws, size_t ws_size,
                              hipStream_t stream)
{
    const float* features = (const float*)d_in[0];
    const int*   nidx     = (const int*)d_in[1];
    const float* W1       = (const float*)d_in[2];
    const float* b1       = (const float*)d_in[3];
    const float* gamma    = (const float*)d_in[4];
    const float* beta     = (const float*)d_in[5];
    const float* mean     = (const float*)d_in[6];
    const float* var      = (const float*)d_in[7];
    const float* Ws       = (const float*)d_in[8];
    const float* Wm       = (const float*)d_in[9];
    const float* bm       = (const float*)d_in[10];
    float* out = (float*)d_out;

    const int N = in_sizes[0] / C_IN;   // 50000

    u16* packed = (u16*)d_ws;                      // N x 512 ([ey|x] bf16)
    u16* W1t    = packed + (size_t)N * 512;        // 256 x 128
    u16* Wst    = W1t + 256 * 128;                 // 256 x 256
    u16* Wmt    = Wst + 256 * 256;                 // 128 x 256

    prep_k<<<dim3(256, 3), 256, 0, stream>>>(W1, Ws, Wm, W1t, Wst, Wmt);

    const int MT = (N + 63) / 64;   // 782

    mlp_k<<<MT, 256, 0, stream>>>(features, W1t, Wst, b1, gamma, beta,
                                  mean, var, packed, N);
    gout_k<<<MT, 256, 0, stream>>>(packed, nidx, Wmt, bm, out, N);
}

// Round 8
// 265.004 us; speedup vs baseline: 1.5060x; 1.5060x over previous
//
#include <hip/hip_runtime.h>
#include <cstddef>

// Problem shape (fixed): N=50000, K=16, C_IN=128, C2=256, C_OUT=128.
#define C_IN  128
#define C2    256
#define C_OUT 128
#define KNBR  16

typedef unsigned short u16;
typedef __attribute__((ext_vector_type(8))) short bf16x8;   // 8 bf16 (4 VGPRs)
typedef __attribute__((ext_vector_type(4))) float f32x4;

__device__ __forceinline__ float bf2f(u16 h) {
    return __uint_as_float(((unsigned int)h) << 16);
}
__device__ __forceinline__ u16 f2bf(float x) {
    unsigned int u = __float_as_uint(x);
    return (u16)((u + 0x7fffu + ((u >> 16) & 1u)) >> 16);
}

// Transpose + convert weights to bf16, n-major [N][K].
__global__ void prep_k(const float* __restrict__ W1, const float* __restrict__ Ws,
                       const float* __restrict__ Wm, u16* __restrict__ W1t,
                       u16* __restrict__ Wst, u16* __restrict__ Wmt)
{
    const int n = blockIdx.x, t = threadIdx.x;
    if (blockIdx.y == 0) {
        if (t < 128) W1t[n * 128 + t] = f2bf(W1[t * 256 + n]);
    } else if (blockIdx.y == 1) {
        Wst[n * 256 + t] = f2bf(Ws[t * 256 + n]);
    } else {
        if (n < 128) Wmt[n * 256 + t] = f2bf(Wm[t * 128 + n]);
    }
}

// Fused MLP, 128-row blocks:
//   x  = BN(relu(F @ W1 + b1))   (GEMM1; x -> LDS xs, then coalesced flush)
//   ey = exp(x @ Ws)             (GEMM2, A from xs; ey -> As reuse, flush)
// packed row (512 u16): [ey[0..255] | x[0..255]], both bf16.
// NOTE: accumulators are declared inside fully-unrolled scopes only --
// indexing an acc array with a non-unrolled loop var spills it to scratch
// (R7 regression: WRITE_SIZE 284 MB, MfmaUtil 2%).
__global__ __launch_bounds__(256)
void mlp_k(const float* __restrict__ F, const u16* __restrict__ W1t,
           const u16* __restrict__ Wst,
           const float* __restrict__ bias, const float* __restrict__ gamma,
           const float* __restrict__ beta, const float* __restrict__ mean,
           const float* __restrict__ var,
           u16* __restrict__ packed, int N)
{
    __shared__ u16 As[128][136];   // features tile (GEMM1); ey tile (GEMM2 epi)
    __shared__ u16 Bs[128][72];    // weight k-slice staging
    __shared__ u16 xs[128][264];   // x tile, full K=256

    const int tid = threadIdx.x;
    const int w = tid >> 6, l = tid & 63, q = l >> 4, r = l & 15;
    const int wm = w & 1, wn = w >> 1;
    const int m0 = blockIdx.x * 128;

    // stage As: 128x128 fp32 -> bf16
    #pragma unroll
    for (int i = 0; i < 16; i++) {
        int idx = tid + i * 256;
        int row = idx >> 5, c4 = (idx & 31) * 4;
        int gm = m0 + row;
        float4 v = make_float4(0.f, 0.f, 0.f, 0.f);
        if (gm < N) v = *(const float4*)(F + (size_t)gm * C_IN + c4);
        ushort4 h;
        h.x = f2bf(v.x); h.y = f2bf(v.y); h.z = f2bf(v.z); h.w = f2bf(v.w);
        *(ushort4*)&As[row][c4] = h;
    }

    // ---- GEMM1: x = F @ W1, two 128-col halves ----
    #pragma unroll 1
    for (int nh = 0; nh < 2; nh++) {
        f32x4 acc[4][4] = {};
        #pragma unroll 1
        for (int k0 = 0; k0 < C_IN; k0 += 64) {
            __syncthreads();   // prior Bs readers done (also covers As stage)
            #pragma unroll
            for (int i = 0; i < 4; i++) {
                int idx = tid + i * 256;
                int row = idx >> 3, g = (idx & 7) * 8;
                *(uint4*)&Bs[row][g] = *(const uint4*)(
                    W1t + (size_t)(nh * 128 + row) * C_IN + k0 + g);
            }
            __syncthreads();
            #pragma unroll
            for (int h = 0; h < 2; h++) {
                bf16x8 af[4], bfr[4];
                #pragma unroll
                for (int i = 0; i < 4; i++)
                    af[i] = *(const bf16x8*)&As[wm * 64 + i * 16 + r][k0 + h * 32 + q * 8];
                #pragma unroll
                for (int j = 0; j < 4; j++)
                    bfr[j] = *(const bf16x8*)&Bs[wn * 64 + j * 16 + r][h * 32 + q * 8];
                #pragma unroll
                for (int i = 0; i < 4; i++)
                    #pragma unroll
                    for (int j = 0; j < 4; j++)
                        acc[i][j] = __builtin_amdgcn_mfma_f32_16x16x32_bf16(
                            af[i], bfr[j], acc[i][j], 0, 0, 0);
            }
        }
        // epilogue 1: BN(relu(z+bias)) -> xs (LDS only)
        #pragma unroll
        for (int j = 0; j < 4; j++) {
            const int ch = nh * 128 + wn * 64 + j * 16 + r;
            const float bi = bias[ch], be = beta[ch], mu = mean[ch];
            const float iv = gamma[ch] * rsqrtf(var[ch] + 1e-5f);
            #pragma unroll
            for (int i = 0; i < 4; i++) {
                const int mb = wm * 64 + i * 16 + q * 4;
                #pragma unroll
                for (int p = 0; p < 4; p++) {
                    float x = fmaxf(acc[i][j][p] + bi, 0.f);
                    x = (x - mu) * iv + be;
                    xs[mb + p][ch] = f2bf(x);
                }
            }
        }
    }
    __syncthreads();   // xs complete
    // coalesced flush: x-half of packed (128 x 256 u16)
    #pragma unroll
    for (int i = 0; i < 16; i++) {
        int idx = tid + i * 256;
        int row = idx >> 4, g = (idx & 15) * 8;   // wait: 256 u16 / 8 = 32 groups
        row = idx >> 5; g = (idx & 31) * 8;
        if (m0 + row < N)
            *(uint4*)(packed + (size_t)(m0 + row) * 512 + 256 + g) =
                *(const uint4*)&xs[row][g];
    }

    // ---- GEMM2: ey = exp(x @ Ws), A from xs, two 128-col halves ----
    #pragma unroll 1
    for (int nh = 0; nh < 2; nh++) {
        f32x4 acc[4][4] = {};
        #pragma unroll 1
        for (int k0 = 0; k0 < C2; k0 += 64) {
            __syncthreads();   // prior Bs readers / As flush-readers done
            #pragma unroll
            for (int i = 0; i < 4; i++) {
                int idx = tid + i * 256;
                int row = idx >> 3, g = (idx & 7) * 8;
                *(uint4*)&Bs[row][g] = *(const uint4*)(
                    Wst + (size_t)(nh * 128 + row) * C2 + k0 + g);
            }
            __syncthreads();
            #pragma unroll
            for (int h = 0; h < 2; h++) {
                bf16x8 af[4], bfr[4];
                #pragma unroll
                for (int i = 0; i < 4; i++)
                    af[i] = *(const bf16x8*)&xs[wm * 64 + i * 16 + r][k0 + h * 32 + q * 8];
                #pragma unroll
                for (int j = 0; j < 4; j++)
                    bfr[j] = *(const bf16x8*)&Bs[wn * 64 + j * 16 + r][h * 32 + q * 8];
                #pragma unroll
                for (int i = 0; i < 4; i++)
                    #pragma unroll
                    for (int j = 0; j < 4; j++)
                        acc[i][j] = __builtin_amdgcn_mfma_f32_16x16x32_bf16(
                            af[i], bfr[j], acc[i][j], 0, 0, 0);
            }
        }
        // epilogue 2: ey -> As reuse (LDS), cols local to this nh-half
        #pragma unroll
        for (int j = 0; j < 4; j++) {
            const int chl = wn * 64 + j * 16 + r;   // 0..127 within half
            #pragma unroll
            for (int i = 0; i < 4; i++) {
                const int mb = wm * 64 + i * 16 + q * 4;
                #pragma unroll
                for (int p = 0; p < 4; p++)
                    As[mb + p][chl] = f2bf(__expf(acc[i][j][p]));
            }
        }
        __syncthreads();   // As (ey half) complete
        // coalesced flush: ey nh-half (128 x 128 u16)
        #pragma unroll
        for (int i = 0; i < 8; i++) {
            int idx = tid + i * 256;
            int row = idx >> 4, g = (idx & 15) * 8;
            if (m0 + row < N)
                *(uint4*)(packed + (size_t)(m0 + row) * 512 + nh * 128 + g) =
                    *(const uint4*)&As[row][g];
        }
    }
}

// Output GEMM: out = featb @ Wm + bm.  A bf16 row-major, Bt n-major bf16.
__global__ __launch_bounds__(256)
void out_gemm(const u16* __restrict__ A, const u16* __restrict__ Bt,
              const float* __restrict__ bias, float* __restrict__ Cf, int N)
{
    __shared__ u16 As[128][72];
    __shared__ u16 Bs[128][72];
    const int tid = threadIdx.x;
    const int w = tid >> 6, l = tid & 63, q = l >> 4, r = l & 15;
    const int wm = w & 1, wn = w >> 1;
    const int m0 = blockIdx.x * 128;

    f32x4 acc[4][4] = {};

    #pragma unroll 1
    for (int k0 = 0; k0 < C2; k0 += 64) {
        #pragma unroll
        for (int i = 0; i < 4; i++) {
            int idx = tid + i * 256;
            int row = idx >> 3, g = (idx & 7) * 8;
            int gm = m0 + row;
            uint4 v = make_uint4(0u, 0u, 0u, 0u);
            if (gm < N) v = *(const uint4*)(A + (size_t)gm * C2 + k0 + g);
            *(uint4*)&As[row][g] = v;
            *(uint4*)&Bs[row][g] = *(const uint4*)(
                Bt + (size_t)row * C2 + k0 + g);   // Wmt is 128 x 256
        }
        __syncthreads();
        #pragma unroll
        for (int h = 0; h < 2; h++) {
            bf16x8 af[4], bfr[4];
            #pragma unroll
            for (int i = 0; i < 4; i++)
                af[i] = *(const bf16x8*)&As[wm * 64 + i * 16 + r][h * 32 + q * 8];
            #pragma unroll
            for (int j = 0; j < 4; j++)
                bfr[j] = *(const bf16x8*)&Bs[wn * 64 + j * 16 + r][h * 32 + q * 8];
            #pragma unroll
            for (int i = 0; i < 4; i++)
                #pragma unroll
                for (int j = 0; j < 4; j++)
                    acc[i][j] = __builtin_amdgcn_mfma_f32_16x16x32_bf16(
                        af[i], bfr[j], acc[i][j], 0, 0, 0);
        }
        __syncthreads();
    }

    #pragma unroll
    for (int j = 0; j < 4; j++) {
        const int ch = wn * 64 + j * 16 + r;
        const float bo = bias[ch];
        #pragma unroll
        for (int i = 0; i < 4; i++) {
            const int mb = m0 + wm * 64 + i * 16 + q * 4;
            #pragma unroll
            for (int p = 0; p < 4; p++) {
                const int m = mb + p;
                if (m < N) Cf[(size_t)m * C_OUT + ch] = acc[i][j][p] + bo;
            }
        }
    }
}

// One wave per point: gather 16 packed rows ([ey|x] halves), 32 8B loads,
// pool = (sum ey*x)/(sum ey) per channel, write bf16 feat.
__global__ __launch_bounds__(256)
void gather_k(const u16* __restrict__ packed, const int* __restrict__ nidx,
              u16* __restrict__ featb, int N)
{
    __shared__ int rows[4 * KNBR];
    const int tid = threadIdx.x;
    const int p0 = blockIdx.x * 4;

    if (tid < 4 * KNBR) {
        int n = p0 + (tid >> 4);
        rows[tid] = (n < N) ? nidx[n * KNBR + (tid & 15)] : 0;
    }
    __syncthreads();

    const int w = tid >> 6;       // wave id -> point p0+w
    const int l = tid & 63;       // channels 4l..4l+3
    const int p = p0 + w;
    if (p >= N) return;

    ushort4 eh[KNBR], xh[KNBR];
    #pragma unroll
    for (int k = 0; k < KNBR; k++) {
        const size_t base = (size_t)rows[w * KNBR + k] * 512;
        eh[k] = *(const ushort4*)(packed + base + l * 4);
        xh[k] = *(const ushort4*)(packed + base + 256 + l * 4);
    }

    float d0 = 0.f, d1 = 0.f, d2 = 0.f, d3 = 0.f;
    float u0 = 0.f, u1 = 0.f, u2 = 0.f, u3 = 0.f;
    #pragma unroll
    for (int k = 0; k < KNBR; k++) {
        float e0 = bf2f(eh[k].x), e1 = bf2f(eh[k].y);
        float e2 = bf2f(eh[k].z), e3 = bf2f(eh[k].w);
        d0 += e0; d1 += e1; d2 += e2; d3 += e3;
        u0 = fmaf(e0, bf2f(xh[k].x), u0);
        u1 = fmaf(e1, bf2f(xh[k].y), u1);
        u2 = fmaf(e2, bf2f(xh[k].z), u2);
        u3 = fmaf(e3, bf2f(xh[k].w), u3);
    }
    ushort4 o;
    o.x = f2bf(u0 / d0); o.y = f2bf(u1 / d1);
    o.z = f2bf(u2 / d2); o.w = f2bf(u3 / d3);
    *(ushort4*)(featb + (size_t)p * C2 + l * 4) = o;
}

extern "C" void kernel_launch(void* const* d_in, const int* in_sizes, int n_in,
                              void* d_out, int out_size, void* d_ws, size_t ws_size,
                              hipStream_t stream)
{
    const float* features = (const float*)d_in[0];
    const int*   nidx     = (const int*)d_in[1];
    const float* W1       = (const float*)d_in[2];
    const float* b1       = (const float*)d_in[3];
    const float* gamma    = (const float*)d_in[4];
    const float* beta     = (const float*)d_in[5];
    const float* mean     = (const float*)d_in[6];
    const float* var      = (const float*)d_in[7];
    const float* Ws       = (const float*)d_in[8];
    const float* Wm       = (const float*)d_in[9];
    const float* bm       = (const float*)d_in[10];
    float* out = (float*)d_out;

    const int N = in_sizes[0] / C_IN;   // 50000

    u16* packed = (u16*)d_ws;                      // N x 512 ([ey|x] bf16)
    u16* W1t    = packed + (size_t)N * 512;        // 256 x 128
    u16* Wst    = W1t + 256 * 128;                 // 256 x 256
    u16* Wmt    = Wst + 256 * 256;                 // 128 x 256
    // feat lives in d_out (bf16 N x 256 == 25.6 MB == out buffer exactly).
    // Safe: out_gemm blocks read all their A rows before overwriting them.
    u16* featb = (u16*)d_out;

    prep_k<<<dim3(256, 3), 256, 0, stream>>>(W1, Ws, Wm, W1t, Wst, Wmt);

    const int MT = (N + 127) / 128;   // 391

    mlp_k<<<MT, 256, 0, stream>>>(features, W1t, Wst, b1, gamma, beta,
                                  mean, var, packed, N);
    gather_k<<<(N + 3) / 4, 256, 0, stream>>>(packed, nidx, featb, N);
    out_gemm<<<MT, 256, 0, stream>>>(featb, Wmt, bm, out, N);
}